// Round 10
// baseline (299.441 us; speedup 1.0000x reference)
//
#include <hip/hip_runtime.h>

// MultiHeadSelfAttention: N=8, C=512, heads=8, d=64, S=1024 (32x32), fp32 in/out.
// R10: R9 persistent mega-kernel with FIXED grid barrier: poll via relaxed
// agent-scope atomic LOAD (R9 polled with atomicAdd RMW -> cross-XCD cacheline
// storm, 244us). Arrival = one atomicAdd per block. Phase bodies unchanged.

typedef _Float16 f16x8 __attribute__((ext_vector_type(8)));
typedef _Float16 f16x4 __attribute__((ext_vector_type(4)));
typedef float f32x4 __attribute__((ext_vector_type(4)));

__device__ inline void gl_lds16(const void* g, void* l) {
  __builtin_amdgcn_global_load_lds((const __attribute__((address_space(1))) void*)g,
                                   (__attribute__((address_space(3))) void*)l, 16, 0, 0);
}

__device__ inline float fexp2(float x) {
#if __has_builtin(__builtin_amdgcn_exp2f)
  return __builtin_amdgcn_exp2f(x);
#else
  return exp2f(x);
#endif
}

// software grid barrier: arrival = 1 device-scope RMW per block; wait = relaxed
// atomic LOAD polling with s_sleep backoff (no RMW storm).
__device__ inline void gbar(unsigned* cnt, unsigned target) {
  __syncthreads();
  if (threadIdx.x == 0) {
    __threadfence();  // release: publish this block's phase writes (agent scope)
    __hip_atomic_fetch_add(cnt, 1u, __ATOMIC_RELAXED, __HIP_MEMORY_SCOPE_AGENT);
    while (__hip_atomic_load(cnt, __ATOMIC_RELAXED, __HIP_MEMORY_SCOPE_AGENT) < target)
      __builtin_amdgcn_s_sleep(16);
    __threadfence();  // acquire: discard stale cached lines before next phase
  }
  __syncthreads();
}

__global__ __launch_bounds__(256, 2) void msa_fused(
    const float* __restrict__ x,
    const float* __restrict__ Wq, const float* __restrict__ bq,
    const float* __restrict__ Wk, const float* __restrict__ bk,
    const float* __restrict__ Wv, const float* __restrict__ bv,
    const float* __restrict__ Wo, const float* __restrict__ bo,
    float* __restrict__ out,
    _Float16* __restrict__ xs16, _Float16* __restrict__ Wqkv16,
    float* __restrict__ bqkv, _Float16* __restrict__ Wo16,
    _Float16* __restrict__ QK, _Float16* __restrict__ Vt,
    unsigned* __restrict__ bar) {
  __shared__ __align__(16) char smem_raw[49152];
  const int tid = threadIdx.x;
  const int bid = blockIdx.x;  // 0..511
  const int lane = tid & 63, wv4 = tid >> 6;
  const int quad = lane >> 4, l15 = lane & 15;

  // ================= Phase 0: prep (x transpose+cast; weight cast) ===========
  {
    const float g = 0.18033688011112042f;  // log2(e)/8
#pragma unroll
    for (int p = 0; p < 2; ++p) {
      int i = (bid + p * 512) * 256 + tid;
      Wqkv16[i]          = (_Float16)(Wq[i] * g);
      Wqkv16[262144 + i] = (_Float16)Wk[i];
      Wqkv16[524288 + i] = (_Float16)Wv[i];
      Wo16[i]            = (_Float16)Wo[i];
      if (i < 512) {
        bqkv[i]        = bq[i] * g;
        bqkv[512 + i]  = bk[i];
        bqkv[1024 + i] = bv[i];
      }
    }
    float (*t)[33] = (float (*)[33])smem_raw;
    const int tx = tid & 31, ty = tid >> 5;
    for (int u = bid; u < 4096; u += 512) {
      int n = u >> 9, c0 = ((u >> 5) & 15) * 32, s0 = (u & 31) * 32;
      __syncthreads();
#pragma unroll
      for (int i = 0; i < 4; ++i) {
        int cc = ty + i * 8;
        t[cc][tx] = x[((size_t)n * 512 + c0 + cc) * 1024 + s0 + tx];
      }
      __syncthreads();
#pragma unroll
      for (int i = 0; i < 4; ++i) {
        int ss = ty + i * 8;
        xs16[((size_t)n * 1024 + s0 + ss) * 512 + c0 + tx] = (_Float16)t[tx][ss];
      }
    }
  }
  gbar(bar + 0, 512);

  // ================= Phase 1: QKV GEMM (BK=64), 768 units over 512 blocks ====
  for (int u = bid; u < 768; u += 512) {
    _Float16* smem = (_Float16*)smem_raw;
    _Float16* As = smem;
    _Float16* Bs = smem + 8192;
    const int bm = (u & 63) * 128, bn = (u >> 6) * 128;
    const int wr = (wv4 >> 1) * 64, wc = (wv4 & 1) * 64;
    f32x4 acc[4][4] = {};
    for (int k0 = 0; k0 < 512; k0 += 64) {
      __syncthreads();
#pragma unroll
      for (int c = 0; c < 4; ++c) {
        int idx = c * 256 + tid;
        int row = idx >> 3, sc = idx & 7;
        int kg = sc ^ (row & 7);
        gl_lds16(xs16 + (size_t)(bm + row) * 512 + k0 + kg * 8, As + idx * 8);
        gl_lds16(Wqkv16 + (size_t)(bn + row) * 512 + k0 + kg * 8, Bs + idx * 8);
      }
      __syncthreads();
#pragma unroll
      for (int kh = 0; kh < 2; ++kh) {
        f16x8 af[4], bf[4];
#pragma unroll
        for (int i = 0; i < 4; ++i) {
          int ra = wr + i * 16 + l15;
          af[i] = *(const f16x8*)(As + ra * 64 + ((kh * 4 + quad) ^ (ra & 7)) * 8);
          int rb = wc + i * 16 + l15;
          bf[i] = *(const f16x8*)(Bs + rb * 64 + ((kh * 4 + quad) ^ (rb & 7)) * 8);
        }
#pragma unroll
        for (int i = 0; i < 4; ++i)
#pragma unroll
          for (int j = 0; j < 4; ++j)
            acc[i][j] = __builtin_amdgcn_mfma_f32_16x16x32_f16(af[i], bf[j], acc[i][j], 0, 0, 0);
      }
    }
    if ((u >> 6) < 8) {
      // Q/K blocks: direct store
#pragma unroll
      for (int j = 0; j < 4; ++j) {
        int col = bn + wc + j * 16 + l15;
        float bb = bqkv[col];
#pragma unroll
        for (int i = 0; i < 4; ++i) {
          int rowb = bm + wr + i * 16 + quad * 4;
#pragma unroll
          for (int r = 0; r < 4; ++r)
            QK[(size_t)(rowb + r) * 1024 + col] = (_Float16)(acc[i][j][r] + bb);
        }
      }
    } else {
      // V blocks: transpose through LDS, store with s-permutation
      __syncthreads();
#pragma unroll
      for (int j = 0; j < 4; ++j) {
        int cl = wc + j * 16 + l15;
        float bb = bqkv[bn + cl];
#pragma unroll
        for (int i = 0; i < 4; ++i) {
          int row = wr + i * 16 + quad * 4;
          f16x4 pk;
#pragma unroll
          for (int r = 0; r < 4; ++r) pk[r] = (_Float16)(acc[i][j][r] + bb);
          *(f16x4*)(smem + cl * 132 + row) = pk;
        }
      }
      __syncthreads();
      const int n = bm >> 10, s0g = bm & 1023;
      const int vh = (bn - 1024) >> 6;
      const int cl = tid >> 1, par = tid & 1;
      const int hh = vh + (cl >> 6), d = cl & 63;
      const size_t vrow = (((size_t)((n * 8 + hh) * 64 + d)) << 10) + s0g;
#pragma unroll
      for (int gq = 0; gq < 8; ++gq) {
        int pb = gq * 16 + par * 8;
        int a32 = pb & ~31, q = (pb >> 3) & 3;
        f16x4 lo = *(const f16x4*)(smem + cl * 132 + a32 + 4 * q);
        f16x4 hi = *(const f16x4*)(smem + cl * 132 + a32 + 16 + 4 * q);
        f16x8 o = {lo[0], lo[1], lo[2], lo[3], hi[0], hi[1], hi[2], hi[3]};
        *(f16x8*)(Vt + vrow + pb) = o;
      }
    }
  }
  gbar(bar + 1, 512);

  // ================= Phase 2: flash attention, 512 units ======================
  {
    _Float16* Qs = (_Float16*)smem_raw;
    _Float16* Ks = Qs + 8192;
    _Float16* Vs = Qs + 16384;
    const int n = (bid >> 3) >> 3, h = (bid >> 3) & 7;
    const int q0 = (bid & 7) * 128;
    __syncthreads();
#pragma unroll
    for (int c = 0; c < 4; ++c) {
      int idx = c * 256 + tid;
      int row = idx >> 3, sc = idx & 7;
      int dg = sc ^ (row & 7);
      gl_lds16(QK + (size_t)(n * 1024 + q0 + row) * 1024 + h * 64 + dg * 8, Qs + idx * 8);
    }
    __syncthreads();
    f16x8 qf[2][2];
#pragma unroll
    for (int mt = 0; mt < 2; ++mt)
#pragma unroll
      for (int dc = 0; dc < 2; ++dc) {
        int row = wv4 * 32 + mt * 16 + l15;
        qf[mt][dc] = *(const f16x8*)(Qs + row * 64 + ((dc * 4 + quad) ^ (row & 7)) * 8);
      }
    f32x4 oaccT[4][2] = {};
    f32x4 lsum[2] = {};
    const f16x8 ones = {(_Float16)1, (_Float16)1, (_Float16)1, (_Float16)1,
                        (_Float16)1, (_Float16)1, (_Float16)1, (_Float16)1};
    for (int kt = 0; kt < 8; ++kt) {
      __syncthreads();
#pragma unroll
      for (int c = 0; c < 4; ++c) {
        int idx = c * 256 + tid;
        int row = idx >> 3, sck = idx & 7;
        int dg = sck ^ (row & 7);
        gl_lds16(QK + (size_t)(n * 1024 + kt * 128 + row) * 1024 + 512 + h * 64 + dg * 8,
                 Ks + idx * 8);
        int d = idx >> 4, scv = idx & 15;
        int vg = scv ^ (d & 7);
        gl_lds16(Vt + (size_t)((n * 8 + h) * 64 + d) * 1024 + kt * 128 + vg * 8,
                 Vs + idx * 8);
      }
      __syncthreads();
#pragma unroll
      for (int sc = 0; sc < 4; ++sc) {
        f32x4 sacc[2][2] = {};
#pragma unroll
        for (int t = 0; t < 2; ++t) {
          int rk = (sc * 2 + t) * 16 + l15;
          f16x8 kf0 = *(const f16x8*)(Ks + rk * 64 + ((quad) ^ (rk & 7)) * 8);
          f16x8 kf1 = *(const f16x8*)(Ks + rk * 64 + ((4 + quad) ^ (rk & 7)) * 8);
#pragma unroll
          for (int mt = 0; mt < 2; ++mt) {
            sacc[mt][t] = __builtin_amdgcn_mfma_f32_16x16x32_f16(kf0, qf[mt][0], sacc[mt][t], 0, 0, 0);
            sacc[mt][t] = __builtin_amdgcn_mfma_f32_16x16x32_f16(kf1, qf[mt][1], sacc[mt][t], 0, 0, 0);
          }
        }
        f16x8 pf[2];
#pragma unroll
        for (int mt = 0; mt < 2; ++mt) {
#pragma unroll
          for (int t = 0; t < 2; ++t)
#pragma unroll
            for (int r = 0; r < 4; ++r)
              pf[mt][t * 4 + r] = (_Float16)fexp2(sacc[mt][t][r]);
          lsum[mt] = __builtin_amdgcn_mfma_f32_16x16x32_f16(pf[mt], ones, lsum[mt], 0, 0, 0);
        }
#pragma unroll
        for (int nt = 0; nt < 4; ++nt) {
          int rd = nt * 16 + l15;
          f16x8 vf = *(const f16x8*)(Vs + rd * 128 + ((sc * 4 + quad) ^ (rd & 7)) * 8);
#pragma unroll
          for (int mt = 0; mt < 2; ++mt)
            oaccT[nt][mt] = __builtin_amdgcn_mfma_f32_16x16x32_f16(vf, pf[mt], oaccT[nt][mt], 0, 0, 0);
        }
      }
    }
    // epilogue: O^T; O16 reuses xs16 (dead after phase 1)
#pragma unroll
    for (int mt = 0; mt < 2; ++mt) {
      int r3 = l15 & 3;
      float lv = lsum[mt][0];
      lv = (r3 == 1) ? lsum[mt][1] : lv;
      lv = (r3 == 2) ? lsum[mt][2] : lv;
      lv = (r3 == 3) ? lsum[mt][3] : lv;
      float lq = __shfl(lv, (l15 >> 2) * 16 + (l15 & 3), 64);
      float rinv = 1.0f / lq;
      int q = q0 + wv4 * 32 + mt * 16 + l15;
      int i = h * 128 + (q >> 3);
      size_t base = (size_t)(n * 1024 + i) * 512 + (q & 7) * 64 + quad * 4;
#pragma unroll
      for (int nt = 0; nt < 4; ++nt) {
        f16x4 pk;
#pragma unroll
        for (int r = 0; r < 4; ++r) pk[r] = (_Float16)(oaccT[nt][mt][r] * rinv);
        *(f16x4*)(xs16 + base + nt * 16) = pk;
      }
    }
  }
  gbar(bar + 2, 512);

  // ================= Phase 3: out GEMM, 256 units =============================
  if (bid < 256) {
    _Float16* As = (_Float16*)smem_raw;
    _Float16* Bs = As + 4096;
    const int bm = (bid & 63) * 128, bn = (bid >> 6) * 128;
    const int wr = (wv4 >> 1) * 64, wc = (wv4 & 1) * 64;
    f32x4 acc[4][4] = {};
    for (int k0 = 0; k0 < 512; k0 += 32) {
      __syncthreads();
#pragma unroll
      for (int c = 0; c < 2; ++c) {
        int idx = c * 256 + tid;
        int row = idx >> 2, sc = idx & 3;
        int kg = sc ^ ((row >> 1) & 3);
        gl_lds16(xs16 + (size_t)(bm + row) * 512 + k0 + kg * 8, As + idx * 8);
        gl_lds16(Wo16 + (size_t)(bn + row) * 512 + k0 + kg * 8, Bs + idx * 8);
      }
      __syncthreads();
      f16x8 af[4], bf[4];
#pragma unroll
      for (int i = 0; i < 4; ++i) {
        int ra = wr + i * 16 + l15;
        af[i] = *(const f16x8*)(As + ra * 32 + (quad ^ ((ra >> 1) & 3)) * 8);
        int rb = wc + i * 16 + l15;
        bf[i] = *(const f16x8*)(Bs + rb * 32 + (quad ^ ((rb >> 1) & 3)) * 8);
      }
#pragma unroll
      for (int i = 0; i < 4; ++i)
#pragma unroll
        for (int j = 0; j < 4; ++j)
          acc[i][j] = __builtin_amdgcn_mfma_f32_16x16x32_f16(af[i], bf[j], acc[i][j], 0, 0, 0);
    }
#pragma unroll
    for (int j = 0; j < 4; ++j) {
      int col = bn + wc + j * 16 + l15;
      float bb = bo[col];
#pragma unroll
      for (int i = 0; i < 4; ++i) {
        int rowb = bm + wr + i * 16 + quad * 4;
#pragma unroll
        for (int r = 0; r < 4; ++r)
          out[(size_t)(rowb + r) * 512 + col] = acc[i][j][r] + bb;
      }
    }
  }
}

extern "C" void kernel_launch(void* const* d_in, const int* in_sizes, int n_in,
                              void* d_out, int out_size, void* d_ws, size_t ws_size,
                              hipStream_t stream) {
  const float* x  = (const float*)d_in[0];
  const float* Wq = (const float*)d_in[1];
  const float* bq = (const float*)d_in[2];
  const float* Wk = (const float*)d_in[3];
  const float* bk = (const float*)d_in[4];
  const float* Wv = (const float*)d_in[5];
  const float* bv = (const float*)d_in[6];
  const float* Wo = (const float*)d_in[7];
  const float* bo = (const float*)d_in[8];
  float* out = (float*)d_out;
  char* ws = (char*)d_ws;

  _Float16* xs16   = (_Float16*)(ws);                          // 8 MB (reused as O16)
  _Float16* QK     = (_Float16*)(ws + (8u << 20));             // 16 MB
  _Float16* Vt     = (_Float16*)(ws + (24u << 20));            // 8 MB
  _Float16* Wqkv16 = (_Float16*)(ws + (32u << 20));            // 1.5 MB
  _Float16* Wo16   = (_Float16*)(ws + (32u << 20) + 1572864);  // 0.5 MB
  float*    bqkv   = (float*)   (ws + (32u << 20) + 2097152);  // 6 KB
  unsigned* bar    = (unsigned*)(ws + (36u << 20));            // 3 counters

  hipMemsetAsync(bar, 0, 256, stream);
  hipLaunchKernelGGL(msa_fused, dim3(512), dim3(256), 0, stream,
                     x, Wq, bq, Wk, bk, Wv, bv, Wo, bo, out,
                     xs16, Wqkv16, bqkv, Wo16, QK, Vt, bar);
}

// Round 11
// 134.619 us; speedup vs baseline: 2.2244x; 2.2244x over previous
//
#include <hip/hip_runtime.h>

// MultiHeadSelfAttention: N=8, C=512, heads=8, d=64, S=1024 (32x32), fp32 in/out.
// R11: R7 structure (4 dispatches — fusion abandoned: agent fences flush L2,
// 666 GB/s latency-bound, m R9/R10 both 244us). NEW: XCD-aware 1-D grids so
// batch n maps to XCD n in ALL kernels (blockIdx%8 heuristic) -> producer ->
// consumer intermediates stay in one XCD's 4MB L2 across dispatches.

typedef _Float16 f16x8 __attribute__((ext_vector_type(8)));
typedef _Float16 f16x4 __attribute__((ext_vector_type(4)));
typedef float f32x4 __attribute__((ext_vector_type(4)));

__device__ inline void gl_lds16(const void* g, void* l) {
  __builtin_amdgcn_global_load_lds((const __attribute__((address_space(1))) void*)g,
                                   (__attribute__((address_space(3))) void*)l, 16, 0, 0);
}

__device__ inline float fexp2(float x) {
#if __has_builtin(__builtin_amdgcn_exp2f)
  return __builtin_amdgcn_exp2f(x);
#else
  return exp2f(x);
#endif
}

// ---------------- prep: x transpose+cast AND weight cast, one kernel ----------
// x-part blocks: bid2&7 = batch n  -> XCD n caches xs16 batch n.
__global__ void prep(const float* __restrict__ x,
                     const float* __restrict__ Wq, const float* __restrict__ bq,
                     const float* __restrict__ Wk, const float* __restrict__ bk,
                     const float* __restrict__ Wv, const float* __restrict__ bv,
                     const float* __restrict__ Wo,
                     _Float16* __restrict__ xs16, _Float16* __restrict__ Wqkv16,
                     float* __restrict__ bqkv, _Float16* __restrict__ Wo16) {
  __shared__ float t[32][33];
  const int tid = threadIdx.x;
  if (blockIdx.x < 1024) {
    const float g = 0.18033688011112042f;  // log2(e)/8
    int i = blockIdx.x * 256 + tid;
    Wqkv16[i]          = (_Float16)(Wq[i] * g);
    Wqkv16[262144 + i] = (_Float16)Wk[i];
    Wqkv16[524288 + i] = (_Float16)Wv[i];
    Wo16[i]            = (_Float16)Wo[i];
    if (i < 512) {
      bqkv[i]        = bq[i] * g;
      bqkv[512 + i]  = bk[i];
      bqkv[1024 + i] = bv[i];
    }
    return;
  }
  const int bid2 = blockIdx.x - 1024;           // 0..4095
  const int n = bid2 & 7;                       // XCD-pinned batch
  const int r = bid2 >> 3;                      // 0..511
  const int c0 = ((r >> 5) & 15) * 32, s0 = (r & 31) * 32;
  const int tx = tid & 31, ty = tid >> 5;       // ty 0..7
#pragma unroll
  for (int i = 0; i < 4; ++i) {
    int cc = ty + i * 8;
    t[cc][tx] = x[((size_t)n * 512 + c0 + cc) * 1024 + s0 + tx];
  }
  __syncthreads();
#pragma unroll
  for (int i = 0; i < 4; ++i) {
    int ss = ty + i * 8;
    xs16[((size_t)n * 1024 + s0 + ss) * 512 + c0 + tx] = (_Float16)t[tx][ss];
  }
}

// ---------------- QKV GEMM: (8192x512)*(1536x512)^T + bias, BK=64 ------------
// 1-D grid 768: xcd = id&7; k = id>>3; bm-tile = xcd*8 + (k&7) (batch = xcd);
// bn-tile = k>>3. Per-XCD: A 1MB + B 1.5MB fits 4MB L2.
__global__ __launch_bounds__(256, 2) void qkv_gemm(
    const _Float16* __restrict__ A, const _Float16* __restrict__ Bw,
    const float* __restrict__ bias, _Float16* __restrict__ QK,
    _Float16* __restrict__ Vt) {
  __shared__ _Float16 smem[16896];  // K-loop: As[0:8192) Bs[8192:16384); epi T 128x132
  _Float16* As = smem;
  _Float16* Bs = smem + 8192;
  const int tid = threadIdx.x;
  const int lane = tid & 63, w = tid >> 6;
  const int quad = lane >> 4, l15 = lane & 15;
  const int id = blockIdx.x;
  const int xcd = id & 7, k = id >> 3;
  const int bm = (xcd * 8 + (k & 7)) * 128;     // batch = xcd
  const int bnt = k >> 3;                       // 0..11
  const int bn = bnt * 128;
  const int wr = (w >> 1) * 64, wc = (w & 1) * 64;
  f32x4 acc[4][4] = {};
  for (int k0 = 0; k0 < 512; k0 += 64) {
    __syncthreads();
#pragma unroll
    for (int c = 0; c < 4; ++c) {
      int idx = c * 256 + tid;          // 0..1023
      int row = idx >> 3, sc = idx & 7;
      int kg = sc ^ (row & 7);          // XOR-chunk swizzle (8 chunks/row)
      gl_lds16(A + (size_t)(bm + row) * 512 + k0 + kg * 8, As + idx * 8);
      gl_lds16(Bw + (size_t)(bn + row) * 512 + k0 + kg * 8, Bs + idx * 8);
    }
    __syncthreads();
#pragma unroll
    for (int kh = 0; kh < 2; ++kh) {
      f16x8 af[4], bf[4];
#pragma unroll
      for (int i = 0; i < 4; ++i) {
        int ra = wr + i * 16 + l15;
        af[i] = *(const f16x8*)(As + ra * 64 + ((kh * 4 + quad) ^ (ra & 7)) * 8);
        int rb = wc + i * 16 + l15;
        bf[i] = *(const f16x8*)(Bs + rb * 64 + ((kh * 4 + quad) ^ (rb & 7)) * 8);
      }
#pragma unroll
      for (int i = 0; i < 4; ++i)
#pragma unroll
        for (int j = 0; j < 4; ++j)
          acc[i][j] = __builtin_amdgcn_mfma_f32_16x16x32_f16(af[i], bf[j], acc[i][j], 0, 0, 0);
    }
  }
  if (bnt < 8) {
    // Q/K blocks: direct store (lanes contiguous in col -> coalesced)
#pragma unroll
    for (int j = 0; j < 4; ++j) {
      int col = bn + wc + j * 16 + l15;
      float bb = bias[col];
#pragma unroll
      for (int i = 0; i < 4; ++i) {
        int rowb = bm + wr + i * 16 + quad * 4;
#pragma unroll
        for (int r = 0; r < 4; ++r)
          QK[(size_t)(rowb + r) * 1024 + col] = (_Float16)(acc[i][j][r] + bb);
      }
    }
  } else {
    // V blocks: transpose tile through LDS, store coalesced with s-permutation
    __syncthreads();  // As/Bs dead; reuse smem as T[col][row], stride 132
#pragma unroll
    for (int j = 0; j < 4; ++j) {
      int cl = wc + j * 16 + l15;
      float bb = bias[bn + cl];
#pragma unroll
      for (int i = 0; i < 4; ++i) {
        int row = wr + i * 16 + quad * 4;
        f16x4 pk;
#pragma unroll
        for (int r = 0; r < 4; ++r) pk[r] = (_Float16)(acc[i][j][r] + bb);
        *(f16x4*)(smem + cl * 132 + row) = pk;
      }
    }
    __syncthreads();
    const int n = bm >> 10, s0g = bm & 1023;
    const int vh = (bn - 1024) >> 6;
    const int cl = tid >> 1, par = tid & 1;
    const int hh = vh + (cl >> 6), d = cl & 63;
    const size_t vrow = (((size_t)((n * 8 + hh) * 64 + d)) << 10) + s0g;
#pragma unroll
    for (int g = 0; g < 8; ++g) {
      int pb = g * 16 + par * 8;
      int a32 = pb & ~31, q = (pb >> 3) & 3;
      f16x4 lo = *(const f16x4*)(smem + cl * 132 + a32 + 4 * q);
      f16x4 hi = *(const f16x4*)(smem + cl * 132 + a32 + 16 + 4 * q);
      f16x8 o = {lo[0], lo[1], lo[2], lo[3], hi[0], hi[1], hi[2], hi[3]};
      *(f16x8*)(Vt + vrow + pb) = o;
    }
  }
}

// ---------------- flash attention: 4 waves, 32 q-rows/wave, O^T epilogue ------
// 1-D grid 512: n = id&7 (XCD-pinned batch), h = (id>>3)&7, q-tile = id>>6.
// Per-XCD: QK[n] 2MB + Vt[n] 1MB fits 4MB L2 (warm from qkv on same XCD).
__global__ __launch_bounds__(256, 2) void attn(
    const _Float16* __restrict__ QK, const _Float16* __restrict__ Vt,
    _Float16* __restrict__ O16) {
  __shared__ _Float16 Qs[128 * 64];
  __shared__ _Float16 Ks[128 * 64];
  __shared__ _Float16 Vs[64 * 128];
  const int tid = threadIdx.x, lane = tid & 63, w = tid >> 6;
  const int quad = lane >> 4, l15 = lane & 15;
  const int id = blockIdx.x;
  const int n = id & 7, h = (id >> 3) & 7;
  const int q0 = (id >> 6) * 128;
#pragma unroll
  for (int c = 0; c < 4; ++c) {
    int idx = c * 256 + tid;
    int row = idx >> 3, sc = idx & 7;
    int dg = sc ^ (row & 7);
    gl_lds16(QK + (size_t)(n * 1024 + q0 + row) * 1024 + h * 64 + dg * 8, Qs + idx * 8);
  }
  __syncthreads();
  f16x8 qf[2][2];
#pragma unroll
  for (int mt = 0; mt < 2; ++mt)
#pragma unroll
    for (int dc = 0; dc < 2; ++dc) {
      int row = w * 32 + mt * 16 + l15;
      qf[mt][dc] = *(const f16x8*)(Qs + row * 64 + ((dc * 4 + quad) ^ (row & 7)) * 8);
    }
  f32x4 oaccT[4][2] = {};  // [nt d-tile][mt q-tile]: rows=d, cols=q
  f32x4 lsum[2] = {};
  const f16x8 ones = {(_Float16)1, (_Float16)1, (_Float16)1, (_Float16)1,
                      (_Float16)1, (_Float16)1, (_Float16)1, (_Float16)1};

  for (int kt = 0; kt < 8; ++kt) {
    __syncthreads();
#pragma unroll
    for (int c = 0; c < 4; ++c) {
      int idx = c * 256 + tid;
      int row = idx >> 3, sck = idx & 7;
      int dg = sck ^ (row & 7);
      gl_lds16(QK + (size_t)(n * 1024 + kt * 128 + row) * 1024 + 512 + h * 64 + dg * 8,
               Ks + idx * 8);
      int d = idx >> 4, scv = idx & 15;
      int vg = scv ^ (d & 7);
      gl_lds16(Vt + (size_t)((n * 8 + h) * 64 + d) * 1024 + kt * 128 + vg * 8,
               Vs + idx * 8);
    }
    __syncthreads();
#pragma unroll
    for (int sc = 0; sc < 4; ++sc) {
      f32x4 sacc[2][2] = {};
#pragma unroll
      for (int t = 0; t < 2; ++t) {
        int rk = (sc * 2 + t) * 16 + l15;
        f16x8 kf0 = *(const f16x8*)(Ks + rk * 64 + ((quad) ^ (rk & 7)) * 8);
        f16x8 kf1 = *(const f16x8*)(Ks + rk * 64 + ((4 + quad) ^ (rk & 7)) * 8);
#pragma unroll
        for (int mt = 0; mt < 2; ++mt) {
          sacc[mt][t] = __builtin_amdgcn_mfma_f32_16x16x32_f16(kf0, qf[mt][0], sacc[mt][t], 0, 0, 0);
          sacc[mt][t] = __builtin_amdgcn_mfma_f32_16x16x32_f16(kf1, qf[mt][1], sacc[mt][t], 0, 0, 0);
        }
      }
      f16x8 pf[2];
#pragma unroll
      for (int mt = 0; mt < 2; ++mt) {
#pragma unroll
        for (int t = 0; t < 2; ++t)
#pragma unroll
          for (int r = 0; r < 4; ++r)
            pf[mt][t * 4 + r] = (_Float16)fexp2(sacc[mt][t][r]);
        lsum[mt] = __builtin_amdgcn_mfma_f32_16x16x32_f16(pf[mt], ones, lsum[mt], 0, 0, 0);
      }
#pragma unroll
      for (int nt = 0; nt < 4; ++nt) {
        int rd = nt * 16 + l15;
        f16x8 vf = *(const f16x8*)(Vs + rd * 128 + ((sc * 4 + quad) ^ (rd & 7)) * 8);
#pragma unroll
        for (int mt = 0; mt < 2; ++mt)
          oaccT[nt][mt] = __builtin_amdgcn_mfma_f32_16x16x32_f16(vf, pf[mt], oaccT[nt][mt], 0, 0, 0);
      }
    }
  }
  // epilogue: O^T layout — lane owns q = q0 + w*32 + mt*16 + l15, d = nt*16+quad*4+r.
#pragma unroll
  for (int mt = 0; mt < 2; ++mt) {
    int r3 = l15 & 3;
    float lv = lsum[mt][0];
    lv = (r3 == 1) ? lsum[mt][1] : lv;
    lv = (r3 == 2) ? lsum[mt][2] : lv;
    lv = (r3 == 3) ? lsum[mt][3] : lv;
    float lq = __shfl(lv, (l15 >> 2) * 16 + (l15 & 3), 64);
    float rinv = 1.0f / lq;
    int q = q0 + w * 32 + mt * 16 + l15;
    int i = h * 128 + (q >> 3);
    size_t base = (size_t)(n * 1024 + i) * 512 + (q & 7) * 64 + quad * 4;
#pragma unroll
    for (int nt = 0; nt < 4; ++nt) {
      f16x4 pk;
#pragma unroll
      for (int r = 0; r < 4; ++r) pk[r] = (_Float16)(oaccT[nt][mt][r] * rinv);
      *(f16x4*)(O16 + base + nt * 16) = pk;
    }
  }
}

// ---------------- out GEMM: (8192x512)*(512x512)^T + bo -> fp32 out ----------
// 1-D grid 256: xcd = id&7; bm-tile = xcd*8 + (k&7) (batch = xcd, warm from
// attn); bn-tile = k>>3. Per-XCD: O16[n] 1MB + Wo 0.5MB.
__global__ __launch_bounds__(256, 2) void out_gemm(
    const _Float16* __restrict__ A, const _Float16* __restrict__ Bw,
    const float* __restrict__ bias, float* __restrict__ out) {
  __shared__ _Float16 As[128 * 32];
  __shared__ _Float16 Bs[128 * 32];
  const int tid = threadIdx.x;
  const int lane = tid & 63, w = tid >> 6;
  const int quad = lane >> 4, l15 = lane & 15;
  const int id = blockIdx.x;
  const int xcd = id & 7, k = id >> 3;
  const int bm = (xcd * 8 + (k & 7)) * 128;
  const int bn = (k >> 3) * 128;
  const int wr = (w >> 1) * 64, wc = (w & 1) * 64;
  f32x4 acc[4][4] = {};
  for (int k0 = 0; k0 < 512; k0 += 32) {
    __syncthreads();
#pragma unroll
    for (int c = 0; c < 2; ++c) {
      int idx = c * 256 + tid;
      int row = idx >> 2, sc = idx & 3;
      int kg = sc ^ ((row >> 1) & 3);
      gl_lds16(A + (size_t)(bm + row) * 512 + k0 + kg * 8, As + idx * 8);
      gl_lds16(Bw + (size_t)(bn + row) * 512 + k0 + kg * 8, Bs + idx * 8);
    }
    __syncthreads();
    f16x8 af[4], bf[4];
#pragma unroll
    for (int i = 0; i < 4; ++i) {
      int ra = wr + i * 16 + l15;
      af[i] = *(const f16x8*)(As + ra * 32 + (quad ^ ((ra >> 1) & 3)) * 8);
      int rb = wc + i * 16 + l15;
      bf[i] = *(const f16x8*)(Bs + rb * 32 + (quad ^ ((rb >> 1) & 3)) * 8);
    }
#pragma unroll
    for (int i = 0; i < 4; ++i)
#pragma unroll
      for (int j = 0; j < 4; ++j)
        acc[i][j] = __builtin_amdgcn_mfma_f32_16x16x32_f16(af[i], bf[j], acc[i][j], 0, 0, 0);
  }
#pragma unroll
  for (int j = 0; j < 4; ++j) {
    int col = bn + wc + j * 16 + l15;
    float bb = bias[col];
#pragma unroll
    for (int i = 0; i < 4; ++i) {
      int rowb = bm + wr + i * 16 + quad * 4;
#pragma unroll
      for (int r = 0; r < 4; ++r)
        out[(size_t)(rowb + r) * 512 + col] = acc[i][j][r] + bb;
    }
  }
}

extern "C" void kernel_launch(void* const* d_in, const int* in_sizes, int n_in,
                              void* d_out, int out_size, void* d_ws, size_t ws_size,
                              hipStream_t stream) {
  const float* x  = (const float*)d_in[0];
  const float* Wq = (const float*)d_in[1];
  const float* bq = (const float*)d_in[2];
  const float* Wk = (const float*)d_in[3];
  const float* bk = (const float*)d_in[4];
  const float* Wv = (const float*)d_in[5];
  const float* bv = (const float*)d_in[6];
  const float* Wo = (const float*)d_in[7];
  const float* bo = (const float*)d_in[8];
  float* out = (float*)d_out;
  char* ws = (char*)d_ws;

  _Float16* xs16   = (_Float16*)(ws);                          // 8 MB (reused as O16)
  _Float16* QK     = (_Float16*)(ws + (8u << 20));             // 16 MB
  _Float16* Vt     = (_Float16*)(ws + (24u << 20));            // 8 MB
  _Float16* Wqkv16 = (_Float16*)(ws + (32u << 20));            // 1.5 MB
  _Float16* Wo16   = (_Float16*)(ws + (32u << 20) + 1572864);  // 0.5 MB
  float*    bqkv   = (float*)   (ws + (32u << 20) + 2097152);  // 6 KB

  hipLaunchKernelGGL(prep, dim3(5120), dim3(256), 0, stream,
                     x, Wq, bq, Wk, bk, Wv, bv, Wo, xs16, Wqkv16, bqkv, Wo16);
  hipLaunchKernelGGL(qkv_gemm, dim3(768), dim3(256), 0, stream,
                     xs16, Wqkv16, bqkv, QK, Vt);
  hipLaunchKernelGGL(attn, dim3(512), dim3(256), 0, stream, QK, Vt, xs16);
  hipLaunchKernelGGL(out_gemm, dim3(256), dim3(256), 0, stream,
                     xs16, Wo16, bo, out);
}